// Round 4
// baseline (4286.142 us; speedup 1.0000x reference)
//
#include <hip/hip_runtime.h>
#include <hip/hip_bf16.h>
#include <hip/hip_fp16.h>

#define FDIM 128
#define NCH 8     // feature chunks
// chunk = 16 floats = 8 float2 / 8 half2 per node

// ---------- degree / dinv ----------

__global__ void degree_kernel(const int* __restrict__ col, int* __restrict__ deg, int E) {
    int e = blockIdx.x * blockDim.x + threadIdx.x;
    if (e < E) atomicAdd(&deg[col[e]], 1);
}

__global__ void dinv_kernel(const int* __restrict__ deg, float* __restrict__ dinv, int N) {
    int i = blockIdx.x * blockDim.x + threadIdx.x;
    if (i < N) {
        int d = deg[i];
        dinv[i] = (d > 0) ? rsqrtf((float)d) : 0.0f;
    }
}

// ---------- exclusive scan of deg -> rowptr ----------

__global__ void scan_blocks_kernel(const int* __restrict__ deg, int* __restrict__ rowptr,
                                   int* __restrict__ bsum, int N) {
    __shared__ int s[256];
    int t = threadIdx.x;
    int i = blockIdx.x * 256 + t;
    int v = (i < N) ? deg[i] : 0;
    s[t] = v;
    __syncthreads();
    for (int off = 1; off < 256; off <<= 1) {
        int add = (t >= off) ? s[t - off] : 0;
        __syncthreads();
        s[t] += add;
        __syncthreads();
    }
    if (i < N) rowptr[i] = s[t] - v;
    if (t == 255) bsum[blockIdx.x] = s[255];
}

__global__ void scan_bsums_kernel(int* __restrict__ bsum, int* __restrict__ boff, int nb) {
    __shared__ int s[512];
    int t = threadIdx.x;
    int v = (t < nb) ? bsum[t] : 0;
    s[t] = v;
    __syncthreads();
    for (int off = 1; off < 512; off <<= 1) {
        int add = (t >= off) ? s[t - off] : 0;
        __syncthreads();
        s[t] += add;
        __syncthreads();
    }
    if (t < nb) boff[t] = s[t] - v;
}

__global__ void add_offsets_kernel(int* __restrict__ rowptr, int* __restrict__ cursor,
                                   const int* __restrict__ boff, int N, int E) {
    int i = blockIdx.x * blockDim.x + threadIdx.x;
    if (i < N) {
        int v = rowptr[i] + boff[i >> 8];
        rowptr[i] = v;
        cursor[i] = v;
    }
    if (i == 0) rowptr[N] = E;
}

// ---------- edge placement: CSR by destination, split idx/weight ----------

__global__ void place_kernel(const int* __restrict__ row, const int* __restrict__ col,
                             const float* __restrict__ dinv, int* __restrict__ cursor,
                             int* __restrict__ eidx, __half* __restrict__ ew, int E) {
    int e = blockIdx.x * blockDim.x + threadIdx.x;
    if (e < E) {
        int r = row[e], c = col[e];
        float w = dinv[r] * dinv[c];
        int pos = atomicAdd(&cursor[c], 1);
        eidx[pos] = r;
        ew[pos] = __float2half(w);
    }
}

// ---------- convert: xh (fp16 chunk-major) ; out init = mf[0]*x ----------
// p indexes float2/half2 elements in chunk-major space [c][node][8]

__global__ void convert_kernel(const float2* __restrict__ x2, const float* __restrict__ mf,
                               __half2* __restrict__ xh, float2* __restrict__ outc,
                               float2* __restrict__ out_nm, int N, long np) {
    long p = (long)blockIdx.x * blockDim.x + threadIdx.x;
    if (p >= np) return;
    long per_chunk = (long)N * 8;
    int c = (int)(p / per_chunk);
    long rem = p - (long)c * per_chunk;
    int node = (int)(rem >> 3);
    int j = (int)(rem & 7);
    long nm = ((long)node << 6) + (c << 3) + j;   // node-major float2 index
    float2 v = x2[nm];
    xh[p] = __floats2half2_rn(v.x, v.y);
    float w = mf[0];
    float2 o = make_float2(w * v.x, w * v.y);
    if (outc) outc[p] = o;
    else      out_nm[nm] = o;
}

// ---------- chunked fused gather prop ----------
// block b: chunk c = b&7 (XCD-affine), 4 waves = 4 dst nodes.
// wave: 8 groups of 8 lanes; group q handles edge e+q; lane j holds half2 (2 feats).
// tgt = scale*gather + beta*prev2 (fp32 chunk-major); shadow fp16; out += coef*tgt.

template <bool COUT>
__global__ __launch_bounds__(256) void prop_chunked_kernel(
        const int* __restrict__ eidx, const __half* __restrict__ ew,
        const int* __restrict__ rowptr,
        const __half2* __restrict__ srch,                 // fp16 chunk-major
        const float2* __restrict__ prev2, int prev2_nm,   // node-major flag (x only)
        float2* __restrict__ tgt, __half2* __restrict__ tgth,
        float2* __restrict__ outv,
        const float* __restrict__ mf, const float* __restrict__ lap,
        int i_coef, float scale, float beta, int N) {
    int b = blockIdx.x;
    int c = b & 7;
    int wid = ((b >> 3) << 2) + (threadIdx.x >> 6);
    if (wid >= N) return;
    int lane = threadIdx.x & 63;
    int q = lane >> 3;
    int j = lane & 7;
    int begin = rowptr[wid], end = rowptr[wid + 1];
    long base = (long)c * N * 8;   // half2 units
    float ax = 0.f, ay = 0.f;
    #pragma unroll 2
    for (int e = begin; e < end; e += 8) {
        int ei = e + q;
        bool valid = ei < end;
        int ii = valid ? ei : begin;
        int idx = eidx[ii];
        float w = valid ? __half2float(ew[ii]) : 0.f;
        __half2 h = srch[base + ((long)idx << 3) + j];
        float2 f = __half22float2(h);
        ax += w * f.x;
        ay += w * f.y;
    }
    // reduce the 8 edge-groups: lanes j<8 end with full sums
    ax += __shfl_down(ax, 8);  ay += __shfl_down(ay, 8);
    ax += __shfl_down(ax, 16); ay += __shfl_down(ay, 16);
    ax += __shfl_down(ax, 32); ay += __shfl_down(ay, 32);
    if (lane < 8) {
        long oc = ((long)c * N + wid) * 8 + j;            // chunk-major float2/half2
        float px = 0.f, py = 0.f;
        if (beta != 0.f) {
            float2 p = prev2_nm ? prev2[((long)wid << 6) + (c << 3) + j] : prev2[oc];
            px = p.x; py = p.y;
        }
        float tx = scale * ax + beta * px;
        float ty = scale * ay + beta * py;
        tgt[oc] = make_float2(tx, ty);
        if (tgth) tgth[oc] = __floats2half2_rn(tx, ty);
        float coef = mf[i_coef] * lap[i_coef - 1];
        long oo = COUT ? oc : (((long)wid << 6) + (c << 3) + j);
        float2 ov = outv[oo];
        ov.x += coef * tx;
        ov.y += coef * ty;
        outv[oo] = ov;
    }
}

// ---------- final: chunk-major outc -> node-major out ----------

__global__ void transpose_out_kernel(const float2* __restrict__ outc,
                                     float2* __restrict__ out, int N, long np) {
    long p = (long)blockIdx.x * blockDim.x + threadIdx.x;  // node-major float2 idx
    if (p >= np) return;
    int node = (int)(p >> 6);
    int f2 = (int)(p & 63);
    int c = f2 >> 3, j = f2 & 7;
    out[p] = outc[((long)c * N + node) * 8 + j];
}

extern "C" void kernel_launch(void* const* d_in, const int* in_sizes, int n_in,
                              void* d_out, int out_size, void* d_ws, size_t ws_size,
                              hipStream_t stream) {
    const float* x   = (const float*)d_in[0];
    const float* mf  = (const float*)d_in[1];
    const float* lap = (const float*)d_in[2];
    const int*   ei  = (const int*)d_in[3];
    float* out = (float*)d_out;

    const int  K  = in_sizes[1] - 1;          // 10
    const long NF = (long)in_sizes[0];        // N*F
    const int  N  = (int)(NF / FDIM);         // 100000
    const int  E  = in_sizes[3] / 2;          // 3200000
    const int* row = ei;
    const int* col = ei + E;

    // workspace layout (256B-aligned bump allocator)
    size_t off = 0;
    auto alloc = [&](size_t bytes) -> void* {
        void* p = (char*)d_ws + off;
        off += (bytes + 255) & ~(size_t)255;
        return p;
    };
    float*  bufA   = (float*)alloc(NF * 4);
    float*  bufB   = (float*)alloc(NF * 4);
    __half* hA     = (__half*)alloc(NF * 2);
    __half* hB     = (__half*)alloc(NF * 2);   // also serves as xh (dead after i=1 before i=2 writes)
    int*    eidx   = (int*)alloc((size_t)E * 4);
    __half* ew     = (__half*)alloc((size_t)E * 2);
    int*    rowptr = (int*)alloc((size_t)(N + 1) * 4);
    int*    cursor = (int*)alloc((size_t)N * 4);
    int*    deg    = (int*)alloc((size_t)N * 4);
    float*  dinv   = (float*)alloc((size_t)N * 4);
    int*    bsum   = (int*)alloc(512 * 4);
    int*    boff   = (int*)alloc(512 * 4);
    // optional chunk-major out accumulator (avoids half-line out traffic per prop)
    float* outc = nullptr;
    if (ws_size >= off + (size_t)NF * 4) outc = (float*)alloc(NF * 4);

    const int BT = 256;
    const int e_blocks = (E + BT - 1) / BT;
    const int n_blocks = (N + BT - 1) / BT;
    const long np = NF / 2;                       // float2/half2 element count
    const int np_blocks = (int)((np + BT - 1) / BT);
    const int g_blocks = NCH * ((N + 3) / 4);     // chunk-affine prop grid

    // CSR build
    hipMemsetAsync(deg, 0, (size_t)N * sizeof(int), stream);
    degree_kernel<<<e_blocks, BT, 0, stream>>>(col, deg, E);
    dinv_kernel<<<n_blocks, BT, 0, stream>>>(deg, dinv, N);
    scan_blocks_kernel<<<n_blocks, BT, 0, stream>>>(deg, rowptr, bsum, N);
    scan_bsums_kernel<<<1, 512, 0, stream>>>(bsum, boff, n_blocks);
    add_offsets_kernel<<<n_blocks, BT, 0, stream>>>(rowptr, cursor, boff, N, E);
    place_kernel<<<e_blocks, BT, 0, stream>>>(row, col, dinv, cursor, eidx, ew, E);

    // xh = fp16 chunk-major copy of x ; out init = mf0*x
    convert_kernel<<<np_blocks, BT, 0, stream>>>((const float2*)x, mf, (__half2*)hB,
                                                 (float2*)outc, (float2*)out, N, np);

    for (int i = 1; i <= K; ++i) {
        const __half* src   = (i == 1) ? hB : ((i % 2 == 0) ? hA : hB);  // shadow(P_{i-1})
        float*        tgt   = (i % 2 == 0) ? bufB : bufA;                // P_i (over P_{i-2})
        __half*       tgth  = (i % 2 == 0) ? hB : hA;
        const float*  prev2 = (i <= 2) ? x : (const float*)tgt;
        int           pnm   = (i <= 2) ? 1 : 0;
        float         scale = (i == 1) ? 1.0f : 2.0f;
        float         beta  = (i == 1) ? 0.0f : -1.0f;
        if (i == K) tgth = nullptr;   // last shadow never gathered
        if (outc) {
            prop_chunked_kernel<true><<<g_blocks, BT, 0, stream>>>(
                eidx, ew, rowptr, (const __half2*)src, (const float2*)prev2, pnm,
                (float2*)tgt, (__half2*)tgth, (float2*)outc, mf, lap, i, scale, beta, N);
        } else {
            prop_chunked_kernel<false><<<g_blocks, BT, 0, stream>>>(
                eidx, ew, rowptr, (const __half2*)src, (const float2*)prev2, pnm,
                (float2*)tgt, (__half2*)tgth, (float2*)out, mf, lap, i, scale, beta, N);
        }
    }

    if (outc) {
        transpose_out_kernel<<<np_blocks, BT, 0, stream>>>((const float2*)outc,
                                                           (float2*)out, N, np);
    }
}